// Round 4
// baseline (642.026 us; speedup 1.0000x reference)
//
#include <hip/hip_runtime.h>

typedef unsigned int uint32;
typedef unsigned short ushort16;

// Problem constants
constexpr int CN0 = 100000;
constexpr int CN1 = 150000;
constexpr int CN2 = 80000;
constexpr int CNE = 1000000;
constexpr int CD  = 128;
constexpr int NBINS = 3 * CN0;                  // 300000 rows across 3 adjacencies
constexpr int TOT_E = 3 * CNE;

// two-level sort params
constexpr int NB    = (NBINS + 511) / 512;      // 586 coarse buckets (bin>>9)
constexpr int CHUNK = 8192;                     // edges per block in hist/reorder
constexpr int G     = (TOT_E + CHUNK - 1) / CHUNK;  // 367 blocks
constexpr int NBG   = NB * G;                   // bucket-major block hist
constexpr int CSCAN_BLOCKS = (NBG + 1023) / 1024;

constexpr size_t align256(size_t x) { return (x + 255) & ~(size_t)255; }

// ---------------- workspace layout (bytes) — peak ~177 MB ----------------
constexpr size_t OFF_H0B = 0;                                          // CN0*CD f16
constexpr size_t OFF_H1B = align256(OFF_H0B + (size_t)CN0 * CD * 2);   // CN1*CD f16
constexpr size_t OFF_H2B = align256(OFF_H1B + (size_t)CN1 * CD * 2);   // CN2*CD f16
constexpr size_t OFF_AG1 = align256(OFF_H2B + (size_t)CN2 * CD * 2);   // CN0*CD f16
constexpr size_t OFF_AG2 = align256(OFF_AG1 + (size_t)CN0 * CD * 2);   // CN0*CD f16
constexpr size_t OFF_A1  = align256(OFF_AG2 + (size_t)CN0 * CD * 2);
constexpr size_t OFF_A2  = align256(OFF_A1 + (size_t)CN0 * 4);
constexpr size_t OFF_RS  = align256(OFF_A2 + (size_t)(CN0 + CN1 + CN2) * 4); // NBINS+1
constexpr size_t OFF_BH  = align256(OFF_RS + (size_t)(NBINS + 1) * 4);       // NBG ints
constexpr size_t OFF_SCL = align256(OFF_BH + (size_t)NBG * 4);               // TOT_E u32
constexpr size_t OFF_BS  = align256(OFF_SCL + (size_t)TOT_E * 4);
// overlay region: bbuf (TOT_E u32, live only during sort) then agg0 panel (CN0*CD f16)
constexpr size_t OFF_BB  = align256(OFF_BS + (size_t)CSCAN_BLOCKS * 4);
constexpr size_t OFF_END = OFF_BB + (size_t)CN0 * CD * 2;  // 25.6 MB > bbuf's 12 MB

// WT overlays (no extra workspace):
//  WT1 (128x128 f16, 32 KB)  -> rs region    (rs not written until finalize)
//  WTA (128x512 f16, 128 KB) -> scols region (scols dead after agg)

// ---------------- f16 helpers ----------------
typedef _Float16 f16x2 __attribute__((ext_vector_type(2)));
typedef _Float16 f16x8 __attribute__((ext_vector_type(8)));
typedef __fp16 fp16x2_builtin __attribute__((ext_vector_type(2)));

__device__ inline ushort16 f2h(float f) {
  union { _Float16 h; ushort16 u; } v; v.h = (_Float16)f; return v.u;
}
__device__ inline uint32 packh2(float a, float b) {
  union { fp16x2_builtin h; uint32 u; } v;
  v.h = __builtin_amdgcn_cvt_pkrtz(a, b);
  return v.u;
}

// ---------------- MFMA types ----------------
typedef float f32x4 __attribute__((ext_vector_type(4)));
union FragU { uint4 q; f16x8 v; ushort16 u[8]; uint32 d[4]; };

// ---------------- W pre-transpose: WT[n][k] = f2h(W[k][n]) ----------------
// WT1: [128][128]  from W1 (128x128);  WTA: [128][512] from Wagg (512x128)
__global__ __launch_bounds__(256) void prep_wt1_kernel(
    const float* __restrict__ W1, ushort16* __restrict__ wt1) {
  int i = blockIdx.x * 256 + threadIdx.x;           // i = n*128 + k
  if (i < 128 * 128) wt1[i] = f2h(W1[(i & 127) * 128 + (i >> 7)]);
}
__global__ __launch_bounds__(256) void prep_wta_kernel(
    const float* __restrict__ Wagg, ushort16* __restrict__ wta) {
  int i = blockIdx.x * 256 + threadIdx.x;           // i = n*512 + k
  if (i < 128 * 512) wta[i] = f2h(Wagg[(i & 511) * 128 + (i >> 9)]);
}

// ---------------- MFMA GEMM (LDS-free): C[M x 128] = concat_K(A panels) @ W ----------
// B fragments load directly from pre-transposed f16 WT ([128][NP*128]) in global;
// WT1 is L1-resident (32 KB), WTA L2-resident. No staging, no barriers, LDS=0.
template <int NP, bool RELU, bool DOT1, bool DOT2, typename TA, typename TC>
__global__ __launch_bounds__(256) void gemm_mfma(
    const TA* __restrict__ A0, const TA* __restrict__ A1,
    const TA* __restrict__ A2, const TA* __restrict__ A3,
    const ushort16* __restrict__ WT, const float* __restrict__ bias,
    TC* __restrict__ C, int M,
    const float* __restrict__ a1w, const float* __restrict__ a2w,
    const float* __restrict__ a1b, const float* __restrict__ a2b,
    float* __restrict__ dot1out, float* __restrict__ dot2out) {
  const int t = threadIdx.x;
  const int wave = t >> 6;
  const int lane = t & 63;
  const int ln = lane & 15;
  const int quad = lane >> 4;
  const int row0 = blockIdx.x * 64;
  const int rowA = row0 + wave * 16 + ln;          // A-fragment row
  const int rA = (rowA < M) ? rowA : (M - 1);      // clamp (garbage rows never stored)
  const int rowC = row0 + wave * 16 + quad * 4;    // C rows rowC..rowC+3

  f32x4 acc[8];
#pragma unroll
  for (int j = 0; j < 8; ++j) acc[j] = (f32x4)(0.f);

#pragma unroll
  for (int p = 0; p < NP; ++p) {
    const TA* __restrict__ Ap = (p == 0) ? A0 : ((p == 1) ? A1 : ((p == 2) ? A2 : A3));
#pragma unroll
    for (int ks = 0; ks < 4; ++ks) {
      const int k0 = ks * 32;
      FragU af;
      if constexpr (sizeof(TA) == 2) {
        af.q = *(const uint4*)((const ushort16*)Ap + (size_t)rA * CD + k0 + quad * 8);
      } else {
        const float* ap = (const float*)Ap + (size_t)rA * CD + k0 + quad * 8;
        float4 f0 = *(const float4*)ap;
        float4 f1 = *(const float4*)(ap + 4);
        af.d[0] = packh2(f0.x, f0.y); af.d[1] = packh2(f0.z, f0.w);
        af.d[2] = packh2(f1.x, f1.y); af.d[3] = packh2(f1.z, f1.w);
      }
#pragma unroll
      for (int j = 0; j < 8; ++j) {
        FragU bf;
        bf.q = *(const uint4*)(WT + (size_t)(j * 16 + ln) * (NP * CD) + p * CD + k0 + quad * 8);
        acc[j] = __builtin_amdgcn_mfma_f32_16x16x32_f16(af.v, bf.v, acc[j], 0, 0, 0);
      }
    }
  }

  // epilogue: bias, activation, store, fused dots
  float s1[4] = {0.f, 0.f, 0.f, 0.f};
  float s2[4] = {0.f, 0.f, 0.f, 0.f};
#pragma unroll
  for (int j = 0; j < 8; ++j) {
    const int n = j * 16 + ln;
    const float bj = bias[n];
    const float a1wj = DOT1 ? a1w[n] : 0.f;
    const float a2wj = DOT2 ? a2w[n] : 0.f;
#pragma unroll
    for (int r = 0; r < 4; ++r) {
      float v = acc[j][r] + bj;
      if constexpr (RELU) v = fmaxf(v, 0.f);
      const int row = rowC + r;
      if (row < M) {
        if constexpr (sizeof(TC) == 2)
          ((ushort16*)C)[(size_t)row * CD + n] = f2h(v);
        else
          ((float*)C)[(size_t)row * CD + n] = v;
      }
      if constexpr (DOT1) s1[r] = fmaf(v, a1wj, s1[r]);
      if constexpr (DOT2) s2[r] = fmaf(v, a2wj, s2[r]);
    }
  }
  if constexpr (DOT1 || DOT2) {
#pragma unroll
    for (int mask = 1; mask < 16; mask <<= 1) {
#pragma unroll
      for (int r = 0; r < 4; ++r) {
        if constexpr (DOT1) s1[r] += __shfl_xor(s1[r], mask);
        if constexpr (DOT2) s2[r] += __shfl_xor(s2[r], mask);
      }
    }
    if (ln == 0) {
#pragma unroll
      for (int r = 0; r < 4; ++r) {
        const int row = rowC + r;
        if (row < M) {
          if constexpr (DOT2) dot2out[row] = s2[r] + a2b[0];
          if constexpr (DOT1) dot1out[row] = s1[r] + a1b[0];
        }
      }
    }
  }
}

// ---------------- two-level counting sort of edges by destination bin ----------------
__device__ inline int edge_bin(int e, const int* r0, const int* r1, const int* r2) {
  if (e < CNE) return r0[e];
  if (e < 2 * CNE) return CN0 + r1[e - CNE];
  return 2 * CN0 + r2[e - 2 * CNE];
}
__device__ inline void edge_get(int e, const int* r0, const int* c0, const int* r1,
                                const int* c1, const int* r2, const int* c2,
                                int& bin, int& col) {
  if (e < CNE) { bin = r0[e]; col = c0[e]; }
  else if (e < 2 * CNE) { bin = CN0 + r1[e - CNE]; col = c1[e - CNE]; }
  else { bin = 2 * CN0 + r2[e - 2 * CNE]; col = c2[e - 2 * CNE]; }
}

__global__ __launch_bounds__(256) void coarse_hist_kernel(
    const int* __restrict__ r0, const int* __restrict__ r1, const int* __restrict__ r2,
    int* __restrict__ blockhist) {
  __shared__ int lh[NB];
  const int t = threadIdx.x;
  for (int i = t; i < NB; i += 256) lh[i] = 0;
  __syncthreads();
  const int e0 = blockIdx.x * CHUNK;
  for (int i = t; i < CHUNK; i += 256) {
    int e = e0 + i;
    if (e < TOT_E) atomicAdd(&lh[edge_bin(e, r0, r1, r2) >> 9], 1);
  }
  __syncthreads();
  for (int i = t; i < NB; i += 256) blockhist[(size_t)i * G + blockIdx.x] = lh[i];
}

__global__ void scan1g_kernel(int* __restrict__ data, int* __restrict__ bsums, int n) {
  __shared__ int lds[256];
  int t = threadIdx.x;
  int idx0 = blockIdx.x * 1024 + t * 4;
  int v[4];
#pragma unroll
  for (int j = 0; j < 4; ++j) v[j] = (idx0 + j < n) ? data[idx0 + j] : 0;
  int tsum = v[0] + v[1] + v[2] + v[3];
  lds[t] = tsum;
  __syncthreads();
  for (int off = 1; off < 256; off <<= 1) {
    int x = (t >= off) ? lds[t - off] : 0;
    __syncthreads();
    lds[t] += x;
    __syncthreads();
  }
  int run = lds[t] - tsum;
  if (t == 255) bsums[blockIdx.x] = lds[255];
#pragma unroll
  for (int j = 0; j < 4; ++j) {
    if (idx0 + j < n) data[idx0 + j] = run;
    run += v[j];
  }
}

__global__ void scan2g_kernel(int* __restrict__ bsums, int nb) {
  __shared__ int lds[512];
  int t = threadIdx.x;
  int v = (t < nb) ? bsums[t] : 0;
  lds[t] = v;
  __syncthreads();
  for (int off = 1; off < 512; off <<= 1) {
    int x = (t >= off) ? lds[t - off] : 0;
    __syncthreads();
    lds[t] += x;
    __syncthreads();
  }
  if (t < nb) bsums[t] = lds[t] - v;
}

__global__ void scan3g_kernel(int* __restrict__ data, const int* __restrict__ bsums, int n) {
  int t = threadIdx.x;
  int idx0 = blockIdx.x * 1024 + t * 4;
  int off = bsums[blockIdx.x];
#pragma unroll
  for (int j = 0; j < 4; ++j)
    if (idx0 + j < n) data[idx0 + j] += off;
}

__global__ __launch_bounds__(256) void reorder_kernel(
    const int* __restrict__ r0, const int* __restrict__ c0,
    const int* __restrict__ r1, const int* __restrict__ c1,
    const int* __restrict__ r2, const int* __restrict__ c2,
    const int* __restrict__ blockscan, uint32* __restrict__ bbuf) {
  __shared__ int lbase[NB];
  const int t = threadIdx.x;
  for (int i = t; i < NB; i += 256) lbase[i] = blockscan[(size_t)i * G + blockIdx.x];
  __syncthreads();
  const int e0 = blockIdx.x * CHUNK;
  for (int i = t; i < CHUNK; i += 256) {
    int e = e0 + i;
    if (e >= TOT_E) break;
    int bin, col;
    edge_get(e, r0, c0, r1, c1, r2, c2, bin, col);
    int pos = atomicAdd(&lbase[bin >> 9], 1);
    bbuf[pos] = ((uint32)(bin & 511) << 18) | (uint32)col;
  }
}

// P4: per-bucket LDS counting sort; fuses attention computation:
// output word = (att_q14 << 18) | col, att_q14 = round-to-nearest 14-bit of sigmoid.
__global__ __launch_bounds__(256) void finalize_kernel(
    const int* __restrict__ blockscan, const uint32* __restrict__ bbuf,
    const float* __restrict__ a1_0, const float* __restrict__ a2all,
    uint32* __restrict__ scols, int* __restrict__ rs) {
  __shared__ int lh[512];
  __shared__ int sc[256];
  const int t = threadIdx.x;
  const int b = blockIdx.x;
  const int binbase = b << 9;
  const int gs = blockscan[(size_t)b * G];
  const int ge = (b == NB - 1) ? TOT_E : blockscan[(size_t)(b + 1) * G];
  const int cnt = ge - gs;

  lh[2 * t] = 0;
  lh[2 * t + 1] = 0;
  __syncthreads();
  for (int i = t; i < cnt; i += 256) atomicAdd(&lh[bbuf[gs + i] >> 18], 1);
  __syncthreads();
  int v0 = lh[2 * t], v1 = lh[2 * t + 1];
  int tsum = v0 + v1;
  sc[t] = tsum;
  __syncthreads();
  for (int off = 1; off < 256; off <<= 1) {
    int x = (t >= off) ? sc[t - off] : 0;
    __syncthreads();
    sc[t] += x;
    __syncthreads();
  }
  int ex = sc[t] - tsum;
  lh[2 * t] = ex;
  lh[2 * t + 1] = ex + v0;
  int nb_here = NBINS - binbase;
  if (2 * t < nb_here) rs[binbase + 2 * t] = gs + ex;
  if (2 * t + 1 < nb_here) rs[binbase + 2 * t + 1] = gs + ex + v0;
  if (b == NB - 1 && t == 255) rs[NBINS] = TOT_E;
  __syncthreads();
  for (int i = t; i < cnt; i += 256) {
    uint32 p = bbuf[gs + i];
    int bl = (int)(p >> 18);
    int col = (int)(p & 0x3FFFFu);
    int gbin = binbase + bl;
    int a = (gbin >= 2 * CN0) ? 2 : ((gbin >= CN0) ? 1 : 0);
    int row = gbin - a * CN0;
    int aoff = (a == 0) ? 0 : ((a == 1) ? CN0 : CN0 + CN1);
    float z = a1_0[row] + a2all[aoff + col];
    float att = 1.0f / (1.0f + __expf(-z));
    int q = (int)(att * 16384.f);
    if (q > 16383) q = 16383;
    int pos = atomicAdd(&lh[bl], 1);
    scols[gs + pos] = ((uint32)q << 18) | (uint32)col;
  }
}

// ---------------- attention aggregation ----------------
// One ROW per 16-lane group (4 rows per wave). Each group's 16 lanes span the
// 128-elem row (dwordx4 = 8 f16/lane) and serially walk the group's edge list.
__global__ __launch_bounds__(256) void agg_kernel_all(
    const int* __restrict__ rs, const uint32* __restrict__ scols,
    const ushort16* __restrict__ h0,
    const ushort16* __restrict__ h1,
    const ushort16* __restrict__ h2,
    ushort16* __restrict__ agg0, ushort16* __restrict__ agg1,
    ushort16* __restrict__ agg2) {
  const int waveid = (blockIdx.x * blockDim.x + threadIdx.x) >> 6;
  const int g = (threadIdx.x >> 4) & 3;   // row-group within wave
  const int ln = threadIdx.x & 15;        // element lane: elems ln*8 .. ln*8+7
  const uint32 eoff = (uint32)ln << 4;    // byte offset within row (16B/lane)

  const int w = waveid * 4 + g;           // global bin for this group
  const bool active = (w < NBINS);
  const int wc = active ? w : (NBINS - 1);

  const int a = (wc >= 2 * CN0) ? 2 : ((wc >= CN0) ? 1 : 0);
  const char* __restrict__ xj =
      (const char*)((a == 0) ? h0 : ((a == 1) ? h1 : h2));
  char* __restrict__ outp = (char*)((a == 0) ? agg0 : ((a == 1) ? agg1 : agg2));
  const int row = wc - a * CN0;

  int s = rs[wc], e = rs[wc + 1];
  if (!active) { s = 0; e = 0; }
  const int pc0 = (e > s) ? (e - 1) : 0;  // clamp target for finished groups

  constexpr float SC = 1.0f / 16384.f;
  float acc[8];
#pragma unroll
  for (int j = 0; j < 8; ++j) acc[j] = 0.f;

  // wave-uniform trip count = max degree over the 4 groups
  int mm = e - s;
  mm = max(mm, __shfl_xor(mm, 16));
  mm = max(mm, __shfl_xor(mm, 32));

  int p = s;
  auto round = [&](int q) {
    const int pc = (q < e) ? q : pc0;
    const uint32 k = scols[pc];
    const uint4 v = *(const uint4*)(xj + (((k & 0x3FFFFu) << 8) | eoff));
    const float tv = fmaf((float)(k >> 18), SC, 0.5f * SC);
    const float t = (q < e) ? tv : 0.f;
    union { uint4 q4; f16x2 h[4]; } u;
    u.q4 = v;
    acc[0] = fmaf((float)u.h[0][0], t, acc[0]);
    acc[1] = fmaf((float)u.h[0][1], t, acc[1]);
    acc[2] = fmaf((float)u.h[1][0], t, acc[2]);
    acc[3] = fmaf((float)u.h[1][1], t, acc[3]);
    acc[4] = fmaf((float)u.h[2][0], t, acc[4]);
    acc[5] = fmaf((float)u.h[2][1], t, acc[5]);
    acc[6] = fmaf((float)u.h[3][0], t, acc[6]);
    acc[7] = fmaf((float)u.h[3][1], t, acc[7]);
  };
  for (int i = 0; i < mm; i += 2) {
    round(p);
    round(p + 1);
    p += 2;
  }

  if (active) {
    uint4 o;
    o.x = packh2(acc[0], acc[1]);
    o.y = packh2(acc[2], acc[3]);
    o.z = packh2(acc[4], acc[5]);
    o.w = packh2(acc[6], acc[7]);
    *(uint4*)(outp + (((size_t)row << 8) | eoff)) = o;
  }
}

// ---------------- launch ----------------
extern "C" void kernel_launch(void* const* d_in, const int* in_sizes, int n_in,
                              void* d_out, int out_size, void* d_ws, size_t ws_size,
                              hipStream_t stream) {
  const float* x0 = (const float*)d_in[0];
  const float* x1 = (const float*)d_in[1];
  const float* x2 = (const float*)d_in[2];
  const float* W1 = (const float*)d_in[3];
  const float* b1 = (const float*)d_in[4];
  const float* a1_w = (const float*)d_in[5];
  const float* a1_b = (const float*)d_in[6];
  const float* a2_w = (const float*)d_in[7];
  const float* a2_b = (const float*)d_in[8];
  const float* Wagg = (const float*)d_in[9];
  const float* bagg = (const float*)d_in[10];
  const int* adj0_r = (const int*)d_in[11];
  const int* adj0_c = (const int*)d_in[12];
  const int* adj1_r = (const int*)d_in[13];
  const int* adj1_c = (const int*)d_in[14];
  const int* adj2_r = (const int*)d_in[15];
  const int* adj2_c = (const int*)d_in[16];
  float* out = (float*)d_out;

  if (ws_size < OFF_END) return;  // tripwire

  char* ws = (char*)d_ws;
  ushort16* h0b    = (ushort16*)(ws + OFF_H0B);
  ushort16* h1b    = (ushort16*)(ws + OFF_H1B);
  ushort16* h2b    = (ushort16*)(ws + OFF_H2B);
  ushort16* agg1b  = (ushort16*)(ws + OFF_AG1);
  ushort16* agg2b  = (ushort16*)(ws + OFF_AG2);
  float*    a1_0   = (float*)(ws + OFF_A1);
  float*    a2all  = (float*)(ws + OFF_A2);
  int*      rs     = (int*)(ws + OFF_RS);
  int*      bh     = (int*)(ws + OFF_BH);
  uint32*   scols  = (uint32*)(ws + OFF_SCL);
  int*      bsums  = (int*)(ws + OFF_BS);
  uint32*   bbuf   = (uint32*)(ws + OFF_BB);     // live only during sort
  ushort16* agg0b  = (ushort16*)(ws + OFF_BB);   // overlays bbuf after finalize
  ushort16* wt1    = (ushort16*)(ws + OFF_RS);   // WT1 overlays rs (rs written later)
  ushort16* wta    = (ushort16*)(ws + OFF_SCL);  // WTA overlays scols (dead after agg)

  // 0) pre-transpose W1 -> f16 WT1 (L1-resident during gemm1)
  prep_wt1_kernel<<<64, 256, 0, stream>>>(W1, wt1);

  // 1) lin1: h = relu(x @ W1 + b1) -> f16, with fused a1/a2 row-dots
  gemm_mfma<1, true, true, true, float, ushort16><<<(CN0 + 63) / 64, 256, 0, stream>>>(
      x0, x0, x0, x0, wt1, b1, h0b, CN0, a1_w, a2_w, a1_b, a2_b, a1_0, a2all);
  gemm_mfma<1, true, false, true, float, ushort16><<<(CN1 + 63) / 64, 256, 0, stream>>>(
      x1, x1, x1, x1, wt1, b1, h1b, CN1, a1_w, a2_w, a1_b, a2_b, a1_0, a2all + CN0);
  gemm_mfma<1, true, false, true, float, ushort16><<<(CN2 + 63) / 64, 256, 0, stream>>>(
      x2, x2, x2, x2, wt1, b1, h2b, CN2, a1_w, a2_w, a1_b, a2_b, a1_0, a2all + CN0 + CN1);

  // 2) two-level counting sort; finalize fuses attention into packed scols
  //    (finalize overwrites the rs region -> WT1 dies here, after its last use)
  coarse_hist_kernel<<<G, 256, 0, stream>>>(adj0_r, adj1_r, adj2_r, bh);
  scan1g_kernel<<<CSCAN_BLOCKS, 256, 0, stream>>>(bh, bsums, NBG);
  scan2g_kernel<<<1, 512, 0, stream>>>(bsums, CSCAN_BLOCKS);
  scan3g_kernel<<<CSCAN_BLOCKS, 256, 0, stream>>>(bh, bsums, NBG);
  reorder_kernel<<<G, 256, 0, stream>>>(adj0_r, adj0_c, adj1_r, adj1_c,
                                        adj2_r, adj2_c, bh, bbuf);
  finalize_kernel<<<NB, 256, 0, stream>>>(bh, bbuf, a1_0, a2all, scols, rs);

  // 3) aggregation: 4 rows per wave (one per 16-lane group), all 3 adjacencies
  {
    const int nwaves = (NBINS + 3) / 4;
    const int nblocks = (nwaves * 64 + 255) / 256;
    agg_kernel_all<<<nblocks, 256, 0, stream>>>(
        rs, scols, h0b, h1b, h2b, agg0b, agg1b, agg2b);
  }

  // 3.5) pre-transpose Wagg -> f16 WTA into the now-dead scols region
  prep_wta_kernel<<<256, 256, 0, stream>>>(Wagg, wta);

  // 4) out = [h0 | agg0 | agg1 | agg2] @ Wagg + bagg  (single K=512 MFMA GEMM)
  gemm_mfma<4, false, false, false, ushort16, float><<<(CN0 + 63) / 64, 256, 0, stream>>>(
      h0b, agg0b, agg1b, agg2b, wta, bagg, out, CN0,
      a1_w, a2_w, a1_b, a2_b, nullptr, nullptr);
}

// Round 5
// 530.345 us; speedup vs baseline: 1.2106x; 1.2106x over previous
//
#include <hip/hip_runtime.h>

typedef unsigned int uint32;
typedef unsigned short ushort16;

// Problem constants
constexpr int CN0 = 100000;
constexpr int CN1 = 150000;
constexpr int CN2 = 80000;
constexpr int CNE = 1000000;
constexpr int CD  = 128;
constexpr int NBINS = 3 * CN0;                  // 300000 rows across 3 adjacencies
constexpr int TOT_E = 3 * CNE;

// two-level sort params
constexpr int NB    = (NBINS + 511) / 512;      // 586 coarse buckets (bin>>9)
constexpr int CHUNK = 8192;                     // edges per block in hist/reorder
constexpr int G     = (TOT_E + CHUNK - 1) / CHUNK;  // 367 blocks
constexpr int NBG   = NB * G;                   // bucket-major block hist
constexpr int CSCAN_BLOCKS = (NBG + 1023) / 1024;

constexpr size_t align256(size_t x) { return (x + 255) & ~(size_t)255; }

// ---------------- workspace layout (bytes) — peak ~177 MB ----------------
constexpr size_t OFF_H0B = 0;                                          // CN0*CD f16
constexpr size_t OFF_H1B = align256(OFF_H0B + (size_t)CN0 * CD * 2);   // CN1*CD f16
constexpr size_t OFF_H2B = align256(OFF_H1B + (size_t)CN1 * CD * 2);   // CN2*CD f16
constexpr size_t OFF_AG1 = align256(OFF_H2B + (size_t)CN2 * CD * 2);   // CN0*CD f16
constexpr size_t OFF_AG2 = align256(OFF_AG1 + (size_t)CN0 * CD * 2);   // CN0*CD f16
constexpr size_t OFF_A1  = align256(OFF_AG2 + (size_t)CN0 * CD * 2);
constexpr size_t OFF_A2  = align256(OFF_A1 + (size_t)CN0 * 4);
constexpr size_t OFF_RS  = align256(OFF_A2 + (size_t)(CN0 + CN1 + CN2) * 4); // NBINS+1
constexpr size_t OFF_BH  = align256(OFF_RS + (size_t)(NBINS + 1) * 4);       // NBG ints
constexpr size_t OFF_SCL = align256(OFF_BH + (size_t)NBG * 4);               // TOT_E u32
constexpr size_t OFF_BS  = align256(OFF_SCL + (size_t)TOT_E * 4);
// overlay region: bbuf (TOT_E u32, live only during sort) then agg0 panel (CN0*CD f16)
constexpr size_t OFF_BB  = align256(OFF_BS + (size_t)CSCAN_BLOCKS * 4);
constexpr size_t OFF_END = OFF_BB + (size_t)CN0 * CD * 2;  // 25.6 MB > bbuf's 12 MB

// WT overlays (no extra workspace):
//  WT1 (128x128 f16, 32 KB)  -> rs region    (rs not written until finalize)
//  WTA (128x512 f16, 128 KB) -> scols region (scols dead after agg)

// ---------------- f16 helpers ----------------
typedef _Float16 f16x2 __attribute__((ext_vector_type(2)));
typedef _Float16 f16x8 __attribute__((ext_vector_type(8)));
typedef __fp16 fp16x2_builtin __attribute__((ext_vector_type(2)));

__device__ inline ushort16 f2h(float f) {
  union { _Float16 h; ushort16 u; } v; v.h = (_Float16)f; return v.u;
}
__device__ inline uint32 packh2(float a, float b) {
  union { fp16x2_builtin h; uint32 u; } v;
  v.h = __builtin_amdgcn_cvt_pkrtz(a, b);
  return v.u;
}

// ---------------- MFMA types ----------------
typedef float f32x4 __attribute__((ext_vector_type(4)));
union FragU { uint4 q; f16x8 v; ushort16 u[8]; uint32 d[4]; };

// ---------------- W pre-transpose: WT[n][k] = f2h(W[k][n]) ----------------
// WT1: [128][128]  from W1 (128x128);  WTA: [128][512] from Wagg (512x128)
__global__ __launch_bounds__(256) void prep_wt1_kernel(
    const float* __restrict__ W1, ushort16* __restrict__ wt1) {
  int i = blockIdx.x * 256 + threadIdx.x;           // i = n*128 + k
  if (i < 128 * 128) wt1[i] = f2h(W1[(i & 127) * 128 + (i >> 7)]);
}
__global__ __launch_bounds__(256) void prep_wta_kernel(
    const float* __restrict__ Wagg, ushort16* __restrict__ wta) {
  int i = blockIdx.x * 256 + threadIdx.x;           // i = n*512 + k
  if (i < 128 * 512) wta[i] = f2h(Wagg[(i & 511) * 128 + (i >> 9)]);
}

// ---------------- MFMA GEMM: C[M x 128] = concat_K(A panels) @ W (+bias) ------------
// B-operand: pre-transposed f16 WT ([128][NP*128]) staged per-panel into LDS via
// wide linear copies (8x dwordx4 -> ds_write_b128 per thread; no cvt, no transpose).
// LDS row stride 144 f16 (18 uint4): staging writes AND fragment reads both spread
// 8 lanes per 4-bank group = conflict-free minimum.
template <int NP, bool RELU, bool DOT1, bool DOT2, typename TA, typename TC>
__global__ __launch_bounds__(256) void gemm_mfma(
    const TA* __restrict__ A0, const TA* __restrict__ A1,
    const TA* __restrict__ A2, const TA* __restrict__ A3,
    const ushort16* __restrict__ WT, const float* __restrict__ bias,
    TC* __restrict__ C, int M,
    const float* __restrict__ a1w, const float* __restrict__ a2w,
    const float* __restrict__ a1b, const float* __restrict__ a2b,
    float* __restrict__ dot1out, float* __restrict__ dot2out) {
  constexpr int WSU = 18;               // uint4 per Wt row (144 f16, +16 pad)
  __shared__ uint4 Wt4[128 * WSU];      // 36 KB

  const int t = threadIdx.x;
  const int wave = t >> 6;
  const int lane = t & 63;
  const int ln = lane & 15;
  const int quad = lane >> 4;
  const int row0 = blockIdx.x * 64;
  const int rowA = row0 + wave * 16 + ln;          // A-fragment row
  const int rA = (rowA < M) ? rowA : (M - 1);      // clamp (garbage rows never stored)
  const int rowC = row0 + wave * 16 + quad * 4;    // C rows rowC..rowC+3

  f32x4 acc[8];
#pragma unroll
  for (int j = 0; j < 8; ++j) acc[j] = (f32x4)(0.f);

#pragma unroll
  for (int p = 0; p < NP; ++p) {
    const TA* __restrict__ Ap = (p == 0) ? A0 : ((p == 1) ? A1 : ((p == 2) ? A2 : A3));
    if (p > 0) __syncthreads();
    // stage 32 KB panel p of WT into LDS (linear copy, 16 B/lane x 8)
#pragma unroll
    for (int i = 0; i < 8; ++i) {
      const int s = t + i * 256;        // uint4 index within panel (16 f16 rows/uint4)
      const int n = s >> 4;             // Wt row
      const int kp = s & 15;            // uint4 col within row
      Wt4[n * WSU + kp] =
          *(const uint4*)(WT + (size_t)n * (NP * CD) + p * CD + kp * 8);
    }
    __syncthreads();
#pragma unroll
    for (int ks = 0; ks < 4; ++ks) {
      const int k0 = ks * 32;
      FragU af;
      if constexpr (sizeof(TA) == 2) {
        af.q = *(const uint4*)((const ushort16*)Ap + (size_t)rA * CD + k0 + quad * 8);
      } else {
        const float* ap = (const float*)Ap + (size_t)rA * CD + k0 + quad * 8;
        float4 f0 = *(const float4*)ap;
        float4 f1 = *(const float4*)(ap + 4);
        af.d[0] = packh2(f0.x, f0.y); af.d[1] = packh2(f0.z, f0.w);
        af.d[2] = packh2(f1.x, f1.y); af.d[3] = packh2(f1.z, f1.w);
      }
#pragma unroll
      for (int j = 0; j < 8; ++j) {
        FragU bf;
        bf.q = Wt4[(j * 16 + ln) * WSU + (k0 >> 3) + quad];
        acc[j] = __builtin_amdgcn_mfma_f32_16x16x32_f16(af.v, bf.v, acc[j], 0, 0, 0);
      }
    }
  }

  // epilogue: bias, activation, store, fused dots
  float s1[4] = {0.f, 0.f, 0.f, 0.f};
  float s2[4] = {0.f, 0.f, 0.f, 0.f};
#pragma unroll
  for (int j = 0; j < 8; ++j) {
    const int n = j * 16 + ln;
    const float bj = bias[n];
    const float a1wj = DOT1 ? a1w[n] : 0.f;
    const float a2wj = DOT2 ? a2w[n] : 0.f;
#pragma unroll
    for (int r = 0; r < 4; ++r) {
      float v = acc[j][r] + bj;
      if constexpr (RELU) v = fmaxf(v, 0.f);
      const int row = rowC + r;
      if (row < M) {
        if constexpr (sizeof(TC) == 2)
          ((ushort16*)C)[(size_t)row * CD + n] = f2h(v);
        else
          ((float*)C)[(size_t)row * CD + n] = v;
      }
      if constexpr (DOT1) s1[r] = fmaf(v, a1wj, s1[r]);
      if constexpr (DOT2) s2[r] = fmaf(v, a2wj, s2[r]);
    }
  }
  if constexpr (DOT1 || DOT2) {
#pragma unroll
    for (int mask = 1; mask < 16; mask <<= 1) {
#pragma unroll
      for (int r = 0; r < 4; ++r) {
        if constexpr (DOT1) s1[r] += __shfl_xor(s1[r], mask);
        if constexpr (DOT2) s2[r] += __shfl_xor(s2[r], mask);
      }
    }
    if (ln == 0) {
#pragma unroll
      for (int r = 0; r < 4; ++r) {
        const int row = rowC + r;
        if (row < M) {
          if constexpr (DOT2) dot2out[row] = s2[r] + a2b[0];
          if constexpr (DOT1) dot1out[row] = s1[r] + a1b[0];
        }
      }
    }
  }
}

// ---------------- two-level counting sort of edges by destination bin ----------------
__device__ inline int edge_bin(int e, const int* r0, const int* r1, const int* r2) {
  if (e < CNE) return r0[e];
  if (e < 2 * CNE) return CN0 + r1[e - CNE];
  return 2 * CN0 + r2[e - 2 * CNE];
}
__device__ inline void edge_get(int e, const int* r0, const int* c0, const int* r1,
                                const int* c1, const int* r2, const int* c2,
                                int& bin, int& col) {
  if (e < CNE) { bin = r0[e]; col = c0[e]; }
  else if (e < 2 * CNE) { bin = CN0 + r1[e - CNE]; col = c1[e - CNE]; }
  else { bin = 2 * CN0 + r2[e - 2 * CNE]; col = c2[e - 2 * CNE]; }
}

__global__ __launch_bounds__(256) void coarse_hist_kernel(
    const int* __restrict__ r0, const int* __restrict__ r1, const int* __restrict__ r2,
    int* __restrict__ blockhist) {
  __shared__ int lh[NB];
  const int t = threadIdx.x;
  for (int i = t; i < NB; i += 256) lh[i] = 0;
  __syncthreads();
  const int e0 = blockIdx.x * CHUNK;
  for (int i = t; i < CHUNK; i += 256) {
    int e = e0 + i;
    if (e < TOT_E) atomicAdd(&lh[edge_bin(e, r0, r1, r2) >> 9], 1);
  }
  __syncthreads();
  for (int i = t; i < NB; i += 256) blockhist[(size_t)i * G + blockIdx.x] = lh[i];
}

__global__ void scan1g_kernel(int* __restrict__ data, int* __restrict__ bsums, int n) {
  __shared__ int lds[256];
  int t = threadIdx.x;
  int idx0 = blockIdx.x * 1024 + t * 4;
  int v[4];
#pragma unroll
  for (int j = 0; j < 4; ++j) v[j] = (idx0 + j < n) ? data[idx0 + j] : 0;
  int tsum = v[0] + v[1] + v[2] + v[3];
  lds[t] = tsum;
  __syncthreads();
  for (int off = 1; off < 256; off <<= 1) {
    int x = (t >= off) ? lds[t - off] : 0;
    __syncthreads();
    lds[t] += x;
    __syncthreads();
  }
  int run = lds[t] - tsum;
  if (t == 255) bsums[blockIdx.x] = lds[255];
#pragma unroll
  for (int j = 0; j < 4; ++j) {
    if (idx0 + j < n) data[idx0 + j] = run;
    run += v[j];
  }
}

__global__ void scan2g_kernel(int* __restrict__ bsums, int nb) {
  __shared__ int lds[512];
  int t = threadIdx.x;
  int v = (t < nb) ? bsums[t] : 0;
  lds[t] = v;
  __syncthreads();
  for (int off = 1; off < 512; off <<= 1) {
    int x = (t >= off) ? lds[t - off] : 0;
    __syncthreads();
    lds[t] += x;
    __syncthreads();
  }
  if (t < nb) bsums[t] = lds[t] - v;
}

__global__ void scan3g_kernel(int* __restrict__ data, const int* __restrict__ bsums, int n) {
  int t = threadIdx.x;
  int idx0 = blockIdx.x * 1024 + t * 4;
  int off = bsums[blockIdx.x];
#pragma unroll
  for (int j = 0; j < 4; ++j)
    if (idx0 + j < n) data[idx0 + j] += off;
}

__global__ __launch_bounds__(256) void reorder_kernel(
    const int* __restrict__ r0, const int* __restrict__ c0,
    const int* __restrict__ r1, const int* __restrict__ c1,
    const int* __restrict__ r2, const int* __restrict__ c2,
    const int* __restrict__ blockscan, uint32* __restrict__ bbuf) {
  __shared__ int lbase[NB];
  const int t = threadIdx.x;
  for (int i = t; i < NB; i += 256) lbase[i] = blockscan[(size_t)i * G + blockIdx.x];
  __syncthreads();
  const int e0 = blockIdx.x * CHUNK;
  for (int i = t; i < CHUNK; i += 256) {
    int e = e0 + i;
    if (e >= TOT_E) break;
    int bin, col;
    edge_get(e, r0, c0, r1, c1, r2, c2, bin, col);
    int pos = atomicAdd(&lbase[bin >> 9], 1);
    bbuf[pos] = ((uint32)(bin & 511) << 18) | (uint32)col;
  }
}

// P4: per-bucket LDS counting sort; fuses attention computation:
// output word = (att_q14 << 18) | col, att_q14 = round-to-nearest 14-bit of sigmoid.
__global__ __launch_bounds__(256) void finalize_kernel(
    const int* __restrict__ blockscan, const uint32* __restrict__ bbuf,
    const float* __restrict__ a1_0, const float* __restrict__ a2all,
    uint32* __restrict__ scols, int* __restrict__ rs) {
  __shared__ int lh[512];
  __shared__ int sc[256];
  const int t = threadIdx.x;
  const int b = blockIdx.x;
  const int binbase = b << 9;
  const int gs = blockscan[(size_t)b * G];
  const int ge = (b == NB - 1) ? TOT_E : blockscan[(size_t)(b + 1) * G];
  const int cnt = ge - gs;

  lh[2 * t] = 0;
  lh[2 * t + 1] = 0;
  __syncthreads();
  for (int i = t; i < cnt; i += 256) atomicAdd(&lh[bbuf[gs + i] >> 18], 1);
  __syncthreads();
  int v0 = lh[2 * t], v1 = lh[2 * t + 1];
  int tsum = v0 + v1;
  sc[t] = tsum;
  __syncthreads();
  for (int off = 1; off < 256; off <<= 1) {
    int x = (t >= off) ? sc[t - off] : 0;
    __syncthreads();
    sc[t] += x;
    __syncthreads();
  }
  int ex = sc[t] - tsum;
  lh[2 * t] = ex;
  lh[2 * t + 1] = ex + v0;
  int nb_here = NBINS - binbase;
  if (2 * t < nb_here) rs[binbase + 2 * t] = gs + ex;
  if (2 * t + 1 < nb_here) rs[binbase + 2 * t + 1] = gs + ex + v0;
  if (b == NB - 1 && t == 255) rs[NBINS] = TOT_E;
  __syncthreads();
  for (int i = t; i < cnt; i += 256) {
    uint32 p = bbuf[gs + i];
    int bl = (int)(p >> 18);
    int col = (int)(p & 0x3FFFFu);
    int gbin = binbase + bl;
    int a = (gbin >= 2 * CN0) ? 2 : ((gbin >= CN0) ? 1 : 0);
    int row = gbin - a * CN0;
    int aoff = (a == 0) ? 0 : ((a == 1) ? CN0 : CN0 + CN1);
    float z = a1_0[row] + a2all[aoff + col];
    float att = 1.0f / (1.0f + __expf(-z));
    int q = (int)(att * 16384.f);
    if (q > 16383) q = 16383;
    int pos = atomicAdd(&lh[bl], 1);
    scols[gs + pos] = ((uint32)q << 18) | (uint32)col;
  }
}

// ---------------- attention aggregation ----------------
// One ROW per 16-lane group (4 rows per wave). Each group's 16 lanes span the
// 128-elem row (dwordx4 = 8 f16/lane) and serially walk the group's edge list.
__global__ __launch_bounds__(256) void agg_kernel_all(
    const int* __restrict__ rs, const uint32* __restrict__ scols,
    const ushort16* __restrict__ h0,
    const ushort16* __restrict__ h1,
    const ushort16* __restrict__ h2,
    ushort16* __restrict__ agg0, ushort16* __restrict__ agg1,
    ushort16* __restrict__ agg2) {
  const int waveid = (blockIdx.x * blockDim.x + threadIdx.x) >> 6;
  const int g = (threadIdx.x >> 4) & 3;   // row-group within wave
  const int ln = threadIdx.x & 15;        // element lane: elems ln*8 .. ln*8+7
  const uint32 eoff = (uint32)ln << 4;    // byte offset within row (16B/lane)

  const int w = waveid * 4 + g;           // global bin for this group
  const bool active = (w < NBINS);
  const int wc = active ? w : (NBINS - 1);

  const int a = (wc >= 2 * CN0) ? 2 : ((wc >= CN0) ? 1 : 0);
  const char* __restrict__ xj =
      (const char*)((a == 0) ? h0 : ((a == 1) ? h1 : h2));
  char* __restrict__ outp = (char*)((a == 0) ? agg0 : ((a == 1) ? agg1 : agg2));
  const int row = wc - a * CN0;

  int s = rs[wc], e = rs[wc + 1];
  if (!active) { s = 0; e = 0; }
  const int pc0 = (e > s) ? (e - 1) : 0;  // clamp target for finished groups

  constexpr float SC = 1.0f / 16384.f;
  float acc[8];
#pragma unroll
  for (int j = 0; j < 8; ++j) acc[j] = 0.f;

  // wave-uniform trip count = max degree over the 4 groups
  int mm = e - s;
  mm = max(mm, __shfl_xor(mm, 16));
  mm = max(mm, __shfl_xor(mm, 32));

  int p = s;
  auto round = [&](int q) {
    const int pc = (q < e) ? q : pc0;
    const uint32 k = scols[pc];
    const uint4 v = *(const uint4*)(xj + (((k & 0x3FFFFu) << 8) | eoff));
    const float tv = fmaf((float)(k >> 18), SC, 0.5f * SC);
    const float t = (q < e) ? tv : 0.f;
    union { uint4 q4; f16x2 h[4]; } u;
    u.q4 = v;
    acc[0] = fmaf((float)u.h[0][0], t, acc[0]);
    acc[1] = fmaf((float)u.h[0][1], t, acc[1]);
    acc[2] = fmaf((float)u.h[1][0], t, acc[2]);
    acc[3] = fmaf((float)u.h[1][1], t, acc[3]);
    acc[4] = fmaf((float)u.h[2][0], t, acc[4]);
    acc[5] = fmaf((float)u.h[2][1], t, acc[5]);
    acc[6] = fmaf((float)u.h[3][0], t, acc[6]);
    acc[7] = fmaf((float)u.h[3][1], t, acc[7]);
  };
  for (int i = 0; i < mm; i += 2) {
    round(p);
    round(p + 1);
    p += 2;
  }

  if (active) {
    uint4 o;
    o.x = packh2(acc[0], acc[1]);
    o.y = packh2(acc[2], acc[3]);
    o.z = packh2(acc[4], acc[5]);
    o.w = packh2(acc[6], acc[7]);
    *(uint4*)(outp + (((size_t)row << 8) | eoff)) = o;
  }
}

// ---------------- launch ----------------
extern "C" void kernel_launch(void* const* d_in, const int* in_sizes, int n_in,
                              void* d_out, int out_size, void* d_ws, size_t ws_size,
                              hipStream_t stream) {
  const float* x0 = (const float*)d_in[0];
  const float* x1 = (const float*)d_in[1];
  const float* x2 = (const float*)d_in[2];
  const float* W1 = (const float*)d_in[3];
  const float* b1 = (const float*)d_in[4];
  const float* a1_w = (const float*)d_in[5];
  const float* a1_b = (const float*)d_in[6];
  const float* a2_w = (const float*)d_in[7];
  const float* a2_b = (const float*)d_in[8];
  const float* Wagg = (const float*)d_in[9];
  const float* bagg = (const float*)d_in[10];
  const int* adj0_r = (const int*)d_in[11];
  const int* adj0_c = (const int*)d_in[12];
  const int* adj1_r = (const int*)d_in[13];
  const int* adj1_c = (const int*)d_in[14];
  const int* adj2_r = (const int*)d_in[15];
  const int* adj2_c = (const int*)d_in[16];
  float* out = (float*)d_out;

  if (ws_size < OFF_END) return;  // tripwire

  char* ws = (char*)d_ws;
  ushort16* h0b    = (ushort16*)(ws + OFF_H0B);
  ushort16* h1b    = (ushort16*)(ws + OFF_H1B);
  ushort16* h2b    = (ushort16*)(ws + OFF_H2B);
  ushort16* agg1b  = (ushort16*)(ws + OFF_AG1);
  ushort16* agg2b  = (ushort16*)(ws + OFF_AG2);
  float*    a1_0   = (float*)(ws + OFF_A1);
  float*    a2all  = (float*)(ws + OFF_A2);
  int*      rs     = (int*)(ws + OFF_RS);
  int*      bh     = (int*)(ws + OFF_BH);
  uint32*   scols  = (uint32*)(ws + OFF_SCL);
  int*      bsums  = (int*)(ws + OFF_BS);
  uint32*   bbuf   = (uint32*)(ws + OFF_BB);     // live only during sort
  ushort16* agg0b  = (ushort16*)(ws + OFF_BB);   // overlays bbuf after finalize
  ushort16* wt1    = (ushort16*)(ws + OFF_RS);   // WT1 overlays rs (rs written later)
  ushort16* wta    = (ushort16*)(ws + OFF_SCL);  // WTA overlays scols (dead after agg)

  // 0) pre-transpose W1 -> f16 WT1
  prep_wt1_kernel<<<64, 256, 0, stream>>>(W1, wt1);

  // 1) lin1: h = relu(x @ W1 + b1) -> f16, with fused a1/a2 row-dots
  gemm_mfma<1, true, true, true, float, ushort16><<<(CN0 + 63) / 64, 256, 0, stream>>>(
      x0, x0, x0, x0, wt1, b1, h0b, CN0, a1_w, a2_w, a1_b, a2_b, a1_0, a2all);
  gemm_mfma<1, true, false, true, float, ushort16><<<(CN1 + 63) / 64, 256, 0, stream>>>(
      x1, x1, x1, x1, wt1, b1, h1b, CN1, a1_w, a2_w, a1_b, a2_b, a1_0, a2all + CN0);
  gemm_mfma<1, true, false, true, float, ushort16><<<(CN2 + 63) / 64, 256, 0, stream>>>(
      x2, x2, x2, x2, wt1, b1, h2b, CN2, a1_w, a2_w, a1_b, a2_b, a1_0, a2all + CN0 + CN1);

  // 2) two-level counting sort; finalize fuses attention into packed scols
  //    (finalize overwrites the rs region -> WT1 dies here, after its last use)
  coarse_hist_kernel<<<G, 256, 0, stream>>>(adj0_r, adj1_r, adj2_r, bh);
  scan1g_kernel<<<CSCAN_BLOCKS, 256, 0, stream>>>(bh, bsums, NBG);
  scan2g_kernel<<<1, 512, 0, stream>>>(bsums, CSCAN_BLOCKS);
  scan3g_kernel<<<CSCAN_BLOCKS, 256, 0, stream>>>(bh, bsums, NBG);
  reorder_kernel<<<G, 256, 0, stream>>>(adj0_r, adj0_c, adj1_r, adj1_c,
                                        adj2_r, adj2_c, bh, bbuf);
  finalize_kernel<<<NB, 256, 0, stream>>>(bh, bbuf, a1_0, a2all, scols, rs);

  // 3) aggregation: 4 rows per wave (one per 16-lane group), all 3 adjacencies
  {
    const int nwaves = (NBINS + 3) / 4;
    const int nblocks = (nwaves * 64 + 255) / 256;
    agg_kernel_all<<<nblocks, 256, 0, stream>>>(
        rs, scols, h0b, h1b, h2b, agg0b, agg1b, agg2b);
  }

  // 3.5) pre-transpose Wagg -> f16 WTA into the now-dead scols region
  prep_wta_kernel<<<256, 256, 0, stream>>>(Wagg, wta);

  // 4) out = [h0 | agg0 | agg1 | agg2] @ Wagg + bagg  (single K=512 MFMA GEMM)
  gemm_mfma<4, false, false, false, ushort16, float><<<(CN0 + 63) / 64, 256, 0, stream>>>(
      h0b, agg0b, agg1b, agg2b, wta, bagg, out, CN0,
      a1_w, a2_w, a1_b, a2_b, nullptr, nullptr);
}

// Round 7
// 522.637 us; speedup vs baseline: 1.2284x; 1.0147x over previous
//
#include <hip/hip_runtime.h>

typedef unsigned int uint32;
typedef unsigned short ushort16;

// Problem constants
constexpr int CN0 = 100000;
constexpr int CN1 = 150000;
constexpr int CN2 = 80000;
constexpr int CNE = 1000000;
constexpr int CD  = 128;
constexpr int NBINS = 3 * CN0;                  // 300000 rows across 3 adjacencies
constexpr int TOT_E = 3 * CNE;

// two-level sort params
constexpr int NB    = (NBINS + 511) / 512;      // 586 coarse buckets (bin>>9)
constexpr int CHUNK = 8192;                     // edges per block in hist/reorder
constexpr int G     = (TOT_E + CHUNK - 1) / CHUNK;  // 367 blocks
constexpr int NBG   = NB * G;                   // bucket-major block hist
constexpr int CSCAN_BLOCKS = (NBG + 1023) / 1024;

constexpr size_t align256(size_t x) { return (x + 255) & ~(size_t)255; }

// ---------------- workspace layout (bytes) — peak ~177 MB ----------------
constexpr size_t OFF_H0B = 0;                                          // CN0*CD f16
constexpr size_t OFF_H1B = align256(OFF_H0B + (size_t)CN0 * CD * 2);   // CN1*CD f16
constexpr size_t OFF_H2B = align256(OFF_H1B + (size_t)CN1 * CD * 2);   // CN2*CD f16
constexpr size_t OFF_AG1 = align256(OFF_H2B + (size_t)CN2 * CD * 2);   // CN0*CD f16
constexpr size_t OFF_AG2 = align256(OFF_AG1 + (size_t)CN0 * CD * 2);   // CN0*CD f16
constexpr size_t OFF_A1  = align256(OFF_AG2 + (size_t)CN0 * CD * 2);
constexpr size_t OFF_A2  = align256(OFF_A1 + (size_t)CN0 * 4);
constexpr size_t OFF_RS  = align256(OFF_A2 + (size_t)(CN0 + CN1 + CN2) * 4); // NBINS+1
constexpr size_t OFF_BH  = align256(OFF_RS + (size_t)(NBINS + 1) * 4);       // NBG ints
constexpr size_t OFF_SCL = align256(OFF_BH + (size_t)NBG * 4);               // TOT_E u32
constexpr size_t OFF_BS  = align256(OFF_SCL + (size_t)TOT_E * 4);
// overlay region: bbuf (TOT_E u32, live only during sort) then agg0 panel (CN0*CD f16)
constexpr size_t OFF_BB  = align256(OFF_BS + (size_t)CSCAN_BLOCKS * 4);
constexpr size_t OFF_END = OFF_BB + (size_t)CN0 * CD * 2;  // 25.6 MB > bbuf's 12 MB

// WT overlays (no extra workspace):
//  WT1 (128x128 f16, 32 KB)  -> rs region    (rs not written until finalize)
//  WTA (128x512 f16, 128 KB) -> scols region (scols dead after agg)

// ---------------- f16 helpers ----------------
typedef _Float16 f16x2 __attribute__((ext_vector_type(2)));
typedef _Float16 f16x8 __attribute__((ext_vector_type(8)));
typedef __fp16 fp16x2_builtin __attribute__((ext_vector_type(2)));

__device__ inline ushort16 f2h(float f) {
  union { _Float16 h; ushort16 u; } v; v.h = (_Float16)f; return v.u;
}
__device__ inline uint32 packh2(float a, float b) {
  union { fp16x2_builtin h; uint32 u; } v;
  v.h = __builtin_amdgcn_cvt_pkrtz(a, b);
  return v.u;
}

// ---------------- MFMA types ----------------
typedef float f32x4 __attribute__((ext_vector_type(4)));
union FragU { uint4 q; f16x8 v; ushort16 u[8]; uint32 d[4]; };

// ---------------- W pre-transpose: WT[n][k] = f2h(W[k][n]) ----------------
__global__ __launch_bounds__(256) void prep_wt1_kernel(
    const float* __restrict__ W1, ushort16* __restrict__ wt1) {
  int i = blockIdx.x * 256 + threadIdx.x;           // i = n*128 + k
  if (i < 128 * 128) wt1[i] = f2h(W1[(i & 127) * 128 + (i >> 7)]);
}
__global__ __launch_bounds__(256) void prep_wta_kernel(
    const float* __restrict__ Wagg, ushort16* __restrict__ wta) {
  int i = blockIdx.x * 256 + threadIdx.x;           // i = n*512 + k
  if (i < 128 * 512) wta[i] = f2h(Wagg[(i & 511) * 128 + (i >> 9)]);
}

// ---------------- MFMA GEMM: C[M x 128] = concat_K(A panels) @ W (+bias) ------------
// BM = 128 rows/block (2 row-tiles per wave) to amortize the per-block LDS stage.
// B-operand: pre-transposed f16 WT ([128][NP*128]) staged per-panel into LDS via
// wide linear copies. LDS row stride 144 f16 (18 uint4): conflict-free minimum.
template <int NP, bool RELU, bool DOT1, bool DOT2, typename TA, typename TC>
__global__ __launch_bounds__(256) void gemm_mfma(
    const TA* __restrict__ A0, const TA* __restrict__ A1,
    const TA* __restrict__ A2, const TA* __restrict__ A3,
    const ushort16* __restrict__ WT, const float* __restrict__ bias,
    TC* __restrict__ C, int M,
    const float* __restrict__ a1w, const float* __restrict__ a2w,
    const float* __restrict__ a1b, const float* __restrict__ a2b,
    float* __restrict__ dot1out, float* __restrict__ dot2out) {
  constexpr int WSU = 18;               // uint4 per Wt row (144 f16, +16 pad)
  __shared__ uint4 Wt4[128 * WSU];      // 36 KB

  const int t = threadIdx.x;
  const int wave = t >> 6;
  const int lane = t & 63;
  const int ln = lane & 15;
  const int quad = lane >> 4;
  const int row0 = blockIdx.x * 128;

  f32x4 acc[2][8];
#pragma unroll
  for (int rt = 0; rt < 2; ++rt)
#pragma unroll
    for (int j = 0; j < 8; ++j) acc[rt][j] = (f32x4)(0.f);

#pragma unroll
  for (int p = 0; p < NP; ++p) {
    const TA* __restrict__ Ap = (p == 0) ? A0 : ((p == 1) ? A1 : ((p == 2) ? A2 : A3));
    if (p > 0) __syncthreads();
    // stage 32 KB panel p of WT into LDS (linear copy, 16 B/lane x 8)
#pragma unroll
    for (int i = 0; i < 8; ++i) {
      const int s = t + i * 256;        // uint4 index within panel
      const int n = s >> 4;             // Wt row
      const int kp = s & 15;            // uint4 col within row
      Wt4[n * WSU + kp] =
          *(const uint4*)(WT + (size_t)n * (NP * CD) + p * CD + kp * 8);
    }
    __syncthreads();
#pragma unroll
    for (int rt = 0; rt < 2; ++rt) {
      const int rowA = row0 + rt * 64 + wave * 16 + ln;
      const int rA = (rowA < M) ? rowA : (M - 1);
#pragma unroll
      for (int ks = 0; ks < 4; ++ks) {
        const int k0 = ks * 32;
        FragU af;
        if constexpr (sizeof(TA) == 2) {
          af.q = *(const uint4*)((const ushort16*)Ap + (size_t)rA * CD + k0 + quad * 8);
        } else {
          const float* ap = (const float*)Ap + (size_t)rA * CD + k0 + quad * 8;
          float4 f0 = *(const float4*)ap;
          float4 f1 = *(const float4*)(ap + 4);
          af.d[0] = packh2(f0.x, f0.y); af.d[1] = packh2(f0.z, f0.w);
          af.d[2] = packh2(f1.x, f1.y); af.d[3] = packh2(f1.z, f1.w);
        }
#pragma unroll
        for (int j = 0; j < 8; ++j) {
          FragU bf;
          bf.q = Wt4[(j * 16 + ln) * WSU + (k0 >> 3) + quad];
          acc[rt][j] = __builtin_amdgcn_mfma_f32_16x16x32_f16(af.v, bf.v, acc[rt][j], 0, 0, 0);
        }
      }
    }
  }

  // epilogue: bias, activation, store, fused dots
  float s1[2][4] = {{0.f, 0.f, 0.f, 0.f}, {0.f, 0.f, 0.f, 0.f}};
  float s2[2][4] = {{0.f, 0.f, 0.f, 0.f}, {0.f, 0.f, 0.f, 0.f}};
#pragma unroll
  for (int rt = 0; rt < 2; ++rt) {
    const int rowC = row0 + rt * 64 + wave * 16 + quad * 4;
#pragma unroll
    for (int j = 0; j < 8; ++j) {
      const int n = j * 16 + ln;
      const float bj = bias[n];
      const float a1wj = DOT1 ? a1w[n] : 0.f;
      const float a2wj = DOT2 ? a2w[n] : 0.f;
#pragma unroll
      for (int r = 0; r < 4; ++r) {
        float v = acc[rt][j][r] + bj;
        if constexpr (RELU) v = fmaxf(v, 0.f);
        const int row = rowC + r;
        if (row < M) {
          if constexpr (sizeof(TC) == 2)
            ((ushort16*)C)[(size_t)row * CD + n] = f2h(v);
          else
            ((float*)C)[(size_t)row * CD + n] = v;
        }
        if constexpr (DOT1) s1[rt][r] = fmaf(v, a1wj, s1[rt][r]);
        if constexpr (DOT2) s2[rt][r] = fmaf(v, a2wj, s2[rt][r]);
      }
    }
  }
  if constexpr (DOT1 || DOT2) {
#pragma unroll
    for (int mask = 1; mask < 16; mask <<= 1) {
#pragma unroll
      for (int rt = 0; rt < 2; ++rt)
#pragma unroll
        for (int r = 0; r < 4; ++r) {
          if constexpr (DOT1) s1[rt][r] += __shfl_xor(s1[rt][r], mask);
          if constexpr (DOT2) s2[rt][r] += __shfl_xor(s2[rt][r], mask);
        }
    }
    if (ln == 0) {
#pragma unroll
      for (int rt = 0; rt < 2; ++rt) {
        const int rowC = row0 + rt * 64 + wave * 16 + quad * 4;
#pragma unroll
        for (int r = 0; r < 4; ++r) {
          const int row = rowC + r;
          if (row < M) {
            if constexpr (DOT2) dot2out[row] = s2[rt][r] + a2b[0];
            if constexpr (DOT1) dot1out[row] = s1[rt][r] + a1b[0];
          }
        }
      }
    }
  }
}

// ---------------- two-level counting sort of edges by destination bin ----------------
__device__ inline int edge_bin(int e, const int* r0, const int* r1, const int* r2) {
  if (e < CNE) return r0[e];
  if (e < 2 * CNE) return CN0 + r1[e - CNE];
  return 2 * CN0 + r2[e - 2 * CNE];
}
__device__ inline void edge_get(int e, const int* r0, const int* c0, const int* r1,
                                const int* c1, const int* r2, const int* c2,
                                int& bin, int& col) {
  if (e < CNE) { bin = r0[e]; col = c0[e]; }
  else if (e < 2 * CNE) { bin = CN0 + r1[e - CNE]; col = c1[e - CNE]; }
  else { bin = 2 * CN0 + r2[e - 2 * CNE]; col = c2[e - 2 * CNE]; }
}

__global__ __launch_bounds__(256) void coarse_hist_kernel(
    const int* __restrict__ r0, const int* __restrict__ r1, const int* __restrict__ r2,
    int* __restrict__ blockhist) {
  __shared__ int lh[NB];
  const int t = threadIdx.x;
  for (int i = t; i < NB; i += 256) lh[i] = 0;
  __syncthreads();
  const int e0 = blockIdx.x * CHUNK;
  for (int i = t; i < CHUNK; i += 256) {
    int e = e0 + i;
    if (e < TOT_E) atomicAdd(&lh[edge_bin(e, r0, r1, r2) >> 9], 1);
  }
  __syncthreads();
  for (int i = t; i < NB; i += 256) blockhist[(size_t)i * G + blockIdx.x] = lh[i];
}

__global__ void scan1g_kernel(int* __restrict__ data, int* __restrict__ bsums, int n) {
  __shared__ int lds[256];
  int t = threadIdx.x;
  int idx0 = blockIdx.x * 1024 + t * 4;
  int v[4];
#pragma unroll
  for (int j = 0; j < 4; ++j) v[j] = (idx0 + j < n) ? data[idx0 + j] : 0;
  int tsum = v[0] + v[1] + v[2] + v[3];
  lds[t] = tsum;
  __syncthreads();
  for (int off = 1; off < 256; off <<= 1) {
    int x = (t >= off) ? lds[t - off] : 0;
    __syncthreads();
    lds[t] += x;
    __syncthreads();
  }
  int run = lds[t] - tsum;
  if (t == 255) bsums[blockIdx.x] = lds[255];
#pragma unroll
  for (int j = 0; j < 4; ++j) {
    if (idx0 + j < n) data[idx0 + j] = run;
    run += v[j];
  }
}

__global__ void scan2g_kernel(int* __restrict__ bsums, int nb) {
  __shared__ int lds[512];
  int t = threadIdx.x;
  int v = (t < nb) ? bsums[t] : 0;
  lds[t] = v;
  __syncthreads();
  for (int off = 1; off < 512; off <<= 1) {
    int x = (t >= off) ? lds[t - off] : 0;
    __syncthreads();
    lds[t] += x;
    __syncthreads();
  }
  if (t < nb) bsums[t] = lds[t] - v;
}

__global__ void scan3g_kernel(int* __restrict__ data, const int* __restrict__ bsums, int n) {
  int t = threadIdx.x;
  int idx0 = blockIdx.x * 1024 + t * 4;
  int off = bsums[blockIdx.x];
#pragma unroll
  for (int j = 0; j < 4; ++j)
    if (idx0 + j < n) data[idx0 + j] += off;
}

__global__ __launch_bounds__(256) void reorder_kernel(
    const int* __restrict__ r0, const int* __restrict__ c0,
    const int* __restrict__ r1, const int* __restrict__ c1,
    const int* __restrict__ r2, const int* __restrict__ c2,
    const int* __restrict__ blockscan, uint32* __restrict__ bbuf) {
  __shared__ int lbase[NB];
  const int t = threadIdx.x;
  for (int i = t; i < NB; i += 256) lbase[i] = blockscan[(size_t)i * G + blockIdx.x];
  __syncthreads();
  const int e0 = blockIdx.x * CHUNK;
  for (int i = t; i < CHUNK; i += 256) {
    int e = e0 + i;
    if (e >= TOT_E) break;
    int bin, col;
    edge_get(e, r0, c0, r1, c1, r2, c2, bin, col);
    int pos = atomicAdd(&lbase[bin >> 9], 1);
    bbuf[pos] = ((uint32)(bin & 511) << 18) | (uint32)col;
  }
}

// P4: per-bucket LDS counting sort; fuses attention computation:
// output word = (att_q14 << 18) | col, att_q14 = round-to-nearest 14-bit of sigmoid.
__global__ __launch_bounds__(256) void finalize_kernel(
    const int* __restrict__ blockscan, const uint32* __restrict__ bbuf,
    const float* __restrict__ a1_0, const float* __restrict__ a2all,
    uint32* __restrict__ scols, int* __restrict__ rs) {
  __shared__ int lh[512];
  __shared__ int sc[256];
  const int t = threadIdx.x;
  const int b = blockIdx.x;
  const int binbase = b << 9;
  const int gs = blockscan[(size_t)b * G];
  const int ge = (b == NB - 1) ? TOT_E : blockscan[(size_t)(b + 1) * G];
  const int cnt = ge - gs;

  lh[2 * t] = 0;
  lh[2 * t + 1] = 0;
  __syncthreads();
  for (int i = t; i < cnt; i += 256) atomicAdd(&lh[bbuf[gs + i] >> 18], 1);
  __syncthreads();
  int v0 = lh[2 * t], v1 = lh[2 * t + 1];
  int tsum = v0 + v1;
  sc[t] = tsum;
  __syncthreads();
  for (int off = 1; off < 256; off <<= 1) {
    int x = (t >= off) ? sc[t - off] : 0;
    __syncthreads();
    sc[t] += x;
    __syncthreads();
  }
  int ex = sc[t] - tsum;
  lh[2 * t] = ex;
  lh[2 * t + 1] = ex + v0;
  int nb_here = NBINS - binbase;
  if (2 * t < nb_here) rs[binbase + 2 * t] = gs + ex;
  if (2 * t + 1 < nb_here) rs[binbase + 2 * t + 1] = gs + ex + v0;
  if (b == NB - 1 && t == 255) rs[NBINS] = TOT_E;
  __syncthreads();
  for (int i = t; i < cnt; i += 256) {
    uint32 p = bbuf[gs + i];
    int bl = (int)(p >> 18);
    int col = (int)(p & 0x3FFFFu);
    int gbin = binbase + bl;
    int a = (gbin >= 2 * CN0) ? 2 : ((gbin >= CN0) ? 1 : 0);
    int row = gbin - a * CN0;
    int aoff = (a == 0) ? 0 : ((a == 1) ? CN0 : CN0 + CN1);
    float z = a1_0[row] + a2all[aoff + col];
    float att = 1.0f / (1.0f + __expf(-z));
    int q = (int)(att * 16384.f);
    if (q > 16383) q = 16383;
    int pos = atomicAdd(&lh[bl], 1);
    scols[gs + pos] = ((uint32)q << 18) | (uint32)col;
  }
}

// ---------------- attention aggregation ----------------
// One ROW per 16-lane group (4 rows per wave). Batch-4 inner loop: 4 independent
// scols loads then 4 independent row gathers in flight (4-deep MLP on the
// dependent scols->gather chain), then 32 fmas. Finished groups clamp to a
// cached row with weight 0.
__global__ __launch_bounds__(256) void agg_kernel_all(
    const int* __restrict__ rs, const uint32* __restrict__ scols,
    const ushort16* __restrict__ h0,
    const ushort16* __restrict__ h1,
    const ushort16* __restrict__ h2,
    ushort16* __restrict__ agg0, ushort16* __restrict__ agg1,
    ushort16* __restrict__ agg2) {
  const int waveid = (blockIdx.x * blockDim.x + threadIdx.x) >> 6;
  const int g = (threadIdx.x >> 4) & 3;   // row-group within wave
  const int ln = threadIdx.x & 15;        // element lane: elems ln*8 .. ln*8+7
  const uint32 eoff = (uint32)ln << 4;    // byte offset within row (16B/lane)

  const int w = waveid * 4 + g;           // global bin for this group
  const bool active = (w < NBINS);
  const int wc = active ? w : (NBINS - 1);

  const int a = (wc >= 2 * CN0) ? 2 : ((wc >= CN0) ? 1 : 0);
  const char* __restrict__ xj =
      (const char*)((a == 0) ? h0 : ((a == 1) ? h1 : h2));
  char* __restrict__ outp = (char*)((a == 0) ? agg0 : ((a == 1) ? agg1 : agg2));
  const int row = wc - a * CN0;

  int s = rs[wc], e = rs[wc + 1];
  if (!active) { s = 0; e = 0; }
  const int pc0 = (e > s) ? (e - 1) : 0;  // clamp target for finished groups

  constexpr float SC = 1.0f / 16384.f;
  float acc[8];
#pragma unroll
  for (int j = 0; j < 8; ++j) acc[j] = 0.f;

  // wave-uniform trip count = max degree over the 4 groups
  int mm = e - s;
  mm = max(mm, __shfl_xor(mm, 16));
  mm = max(mm, __shfl_xor(mm, 32));

  int p = s;
  for (int i = 0; i < mm; i += 4) {
    const int c0 = (p < e) ? p : pc0;
    const int c1 = (p + 1 < e) ? p + 1 : pc0;
    const int c2 = (p + 2 < e) ? p + 2 : pc0;
    const int c3 = (p + 3 < e) ? p + 3 : pc0;
    const uint32 k0 = scols[c0];
    const uint32 k1 = scols[c1];
    const uint32 k2 = scols[c2];
    const uint32 k3 = scols[c3];
    union { uint4 q4; f16x2 h[4]; } u0, u1, u2, u3;
    u0.q4 = *(const uint4*)(xj + (((k0 & 0x3FFFFu) << 8) | eoff));
    u1.q4 = *(const uint4*)(xj + (((k1 & 0x3FFFFu) << 8) | eoff));
    u2.q4 = *(const uint4*)(xj + (((k2 & 0x3FFFFu) << 8) | eoff));
    u3.q4 = *(const uint4*)(xj + (((k3 & 0x3FFFFu) << 8) | eoff));
    const float t0 = (p < e) ? fmaf((float)(k0 >> 18), SC, 0.5f * SC) : 0.f;
    const float t1 = (p + 1 < e) ? fmaf((float)(k1 >> 18), SC, 0.5f * SC) : 0.f;
    const float t2 = (p + 2 < e) ? fmaf((float)(k2 >> 18), SC, 0.5f * SC) : 0.f;
    const float t3 = (p + 3 < e) ? fmaf((float)(k3 >> 18), SC, 0.5f * SC) : 0.f;
#pragma unroll
    for (int j = 0; j < 4; ++j) {
      acc[2 * j]     = fmaf((float)u0.h[j][0], t0, acc[2 * j]);
      acc[2 * j + 1] = fmaf((float)u0.h[j][1], t0, acc[2 * j + 1]);
      acc[2 * j]     = fmaf((float)u1.h[j][0], t1, acc[2 * j]);
      acc[2 * j + 1] = fmaf((float)u1.h[j][1], t1, acc[2 * j + 1]);
      acc[2 * j]     = fmaf((float)u2.h[j][0], t2, acc[2 * j]);
      acc[2 * j + 1] = fmaf((float)u2.h[j][1], t2, acc[2 * j + 1]);
      acc[2 * j]     = fmaf((float)u3.h[j][0], t3, acc[2 * j]);
      acc[2 * j + 1] = fmaf((float)u3.h[j][1], t3, acc[2 * j + 1]);
    }
    p += 4;
  }

  if (active) {
    uint4 o;
    o.x = packh2(acc[0], acc[1]);
    o.y = packh2(acc[2], acc[3]);
    o.z = packh2(acc[4], acc[5]);
    o.w = packh2(acc[6], acc[7]);
    *(uint4*)(outp + (((size_t)row << 8) | eoff)) = o;
  }
}

// ---------------- launch ----------------
extern "C" void kernel_launch(void* const* d_in, const int* in_sizes, int n_in,
                              void* d_out, int out_size, void* d_ws, size_t ws_size,
                              hipStream_t stream) {
  const float* x0 = (const float*)d_in[0];
  const float* x1 = (const float*)d_in[1];
  const float* x2 = (const float*)d_in[2];
  const float* W1 = (const float*)d_in[3];
  const float* b1 = (const float*)d_in[4];
  const float* a1_w = (const float*)d_in[5];
  const float* a1_b = (const float*)d_in[6];
  const float* a2_w = (const float*)d_in[7];
  const float* a2_b = (const float*)d_in[8];
  const float* Wagg = (const float*)d_in[9];
  const float* bagg = (const float*)d_in[10];
  const int* adj0_r = (const int*)d_in[11];
  const int* adj0_c = (const int*)d_in[12];
  const int* adj1_r = (const int*)d_in[13];
  const int* adj1_c = (const int*)d_in[14];
  const int* adj2_r = (const int*)d_in[15];
  const int* adj2_c = (const int*)d_in[16];
  float* out = (float*)d_out;

  if (ws_size < OFF_END) return;  // tripwire

  char* ws = (char*)d_ws;
  ushort16* h0b    = (ushort16*)(ws + OFF_H0B);
  ushort16* h1b    = (ushort16*)(ws + OFF_H1B);
  ushort16* h2b    = (ushort16*)(ws + OFF_H2B);
  ushort16* agg1b  = (ushort16*)(ws + OFF_AG1);
  ushort16* agg2b  = (ushort16*)(ws + OFF_AG2);
  float*    a1_0   = (float*)(ws + OFF_A1);
  float*    a2all  = (float*)(ws + OFF_A2);
  int*      rs     = (int*)(ws + OFF_RS);
  int*      bh     = (int*)(ws + OFF_BH);
  uint32*   scols  = (uint32*)(ws + OFF_SCL);
  int*      bsums  = (int*)(ws + OFF_BS);
  uint32*   bbuf   = (uint32*)(ws + OFF_BB);     // live only during sort
  ushort16* agg0b  = (ushort16*)(ws + OFF_BB);   // overlays bbuf after finalize
  ushort16* wt1    = (ushort16*)(ws + OFF_RS);   // WT1 overlays rs (rs written later)
  ushort16* wta    = (ushort16*)(ws + OFF_SCL);  // WTA overlays scols (dead after agg)

  // 0) pre-transpose W1 -> f16 WT1
  prep_wt1_kernel<<<64, 256, 0, stream>>>(W1, wt1);

  // 1) lin1: h = relu(x @ W1 + b1) -> f16, with fused a1/a2 row-dots
  gemm_mfma<1, true, true, true, float, ushort16><<<(CN0 + 127) / 128, 256, 0, stream>>>(
      x0, x0, x0, x0, wt1, b1, h0b, CN0, a1_w, a2_w, a1_b, a2_b, a1_0, a2all);
  gemm_mfma<1, true, false, true, float, ushort16><<<(CN1 + 127) / 128, 256, 0, stream>>>(
      x1, x1, x1, x1, wt1, b1, h1b, CN1, a1_w, a2_w, a1_b, a2_b, a1_0, a2all + CN0);
  gemm_mfma<1, true, false, true, float, ushort16><<<(CN2 + 127) / 128, 256, 0, stream>>>(
      x2, x2, x2, x2, wt1, b1, h2b, CN2, a1_w, a2_w, a1_b, a2_b, a1_0, a2all + CN0 + CN1);

  // 2) two-level counting sort; finalize fuses attention into packed scols
  //    (finalize overwrites the rs region -> WT1 dies here, after its last use)
  coarse_hist_kernel<<<G, 256, 0, stream>>>(adj0_r, adj1_r, adj2_r, bh);
  scan1g_kernel<<<CSCAN_BLOCKS, 256, 0, stream>>>(bh, bsums, NBG);
  scan2g_kernel<<<1, 512, 0, stream>>>(bsums, CSCAN_BLOCKS);
  scan3g_kernel<<<CSCAN_BLOCKS, 256, 0, stream>>>(bh, bsums, NBG);
  reorder_kernel<<<G, 256, 0, stream>>>(adj0_r, adj0_c, adj1_r, adj1_c,
                                        adj2_r, adj2_c, bh, bbuf);
  finalize_kernel<<<NB, 256, 0, stream>>>(bh, bbuf, a1_0, a2all, scols, rs);

  // 3) aggregation: 4 rows per wave (one per 16-lane group), all 3 adjacencies
  {
    const int nwaves = (NBINS + 3) / 4;
    const int nblocks = (nwaves * 64 + 255) / 256;
    agg_kernel_all<<<nblocks, 256, 0, stream>>>(
        rs, scols, h0b, h1b, h2b, agg0b, agg1b, agg2b);
  }

  // 3.5) pre-transpose Wagg -> f16 WTA into the now-dead scols region
  prep_wta_kernel<<<256, 256, 0, stream>>>(Wagg, wta);

  // 4) out = [h0 | agg0 | agg1 | agg2] @ Wagg + bagg  (single K=512 MFMA GEMM)
  gemm_mfma<4, false, false, false, ushort16, float><<<(CN0 + 127) / 128, 256, 0, stream>>>(
      h0b, agg0b, agg1b, agg2b, wta, bagg, out, CN0,
      a1_w, a2_w, a1_b, a2_b, nullptr, nullptr);
}